// Round 6
// baseline (171.164 us; speedup 1.0000x reference)
//
#include <hip/hip_runtime.h>
#include <hip/hip_bf16.h>

#define NN 2048
typedef unsigned short u16;
typedef unsigned long long u64;
typedef __attribute__((ext_vector_type(8))) short short8;
typedef __attribute__((ext_vector_type(4))) float f32x4;

// monotone float<->uint map for atomicMax on floats; 0 < fmono(any finite)
__device__ __forceinline__ unsigned fmono(float x) {
    unsigned b = __float_as_uint(x);
    return (b & 0x80000000u) ? ~b : (b | 0x80000000u);
}
__device__ __forceinline__ float fmono_inv(unsigned u) {
    return (u & 0x80000000u) ? __uint_as_float(u ^ 0x80000000u) : __uint_as_float(~u);
}
// fp32 -> bf16 bits, RNE
__device__ __forceinline__ unsigned bfb(float x) {
    unsigned u = __float_as_uint(x);
    return (u + 0x7FFFu + ((u >> 16) & 1u)) >> 16;
}

// ---------------- prep: adj bitmask + bf16 conversions (x, W1^T, W2^T), one dispatch ----------------
__global__ __launch_bounds__(256) void prep(const float* __restrict__ x,
                                            const float* __restrict__ W1,
                                            const float* __restrict__ W2,
                                            const int* __restrict__ adj,
                                            u16* __restrict__ xb, u16* __restrict__ w1t,
                                            u16* __restrict__ w2t, u64* __restrict__ ab) {
    const int b = blockIdx.x;
    if (b < 16384) {                         // adj bits: 4M threads
        int t = b * 256 + threadIdx.x;
        int W = t >> 6, lane = t & 63;
        int i = W >> 5, jw = W & 31;
        int a = adj[(size_t)i * NN + jw * 64 + lane];
        u64 m = __ballot(a != 0);
        if (lane == 0) ab[(size_t)i * 32 + jw] = m;
    } else if (b < 16384 + 1024) {           // x: 2048x512 -> bf16, float4/thread
        int t = (b - 16384) * 256 + threadIdx.x;
        float4 v = ((const float4*)x)[t];
        uint2 o;
        o.x = bfb(v.x) | (bfb(v.y) << 16);
        o.y = bfb(v.z) | (bfb(v.w) << 16);
        ((uint2*)xb)[t] = o;
    } else if (b < 16384 + 1024 + 512) {     // w1t[c][k] = W1[k][c], 256x512
        int u = (b - 17408) * 256 + threadIdx.x;
        int c = u >> 9, k = u & 511;
        w1t[u] = (u16)bfb(W1[(size_t)k * 256 + c]);
    } else {                                 // w2t[c][k] = W2[k][c], 128x256
        int u = (b - 17920) * 256 + threadIdx.x;
        int c = u >> 8, k = u & 255;
        w2t[u] = (u16)bfb(W2[(size_t)k * 128 + c]);
    }
}

// ---------------- gemm1 fused: gbt1 = (x@W1)^T bf16, + el1/ert1/ermax1 in epilogue ----------------
// grid 128 x 512thr: block = 16 rows x 256 cols; wave w = head w (cols w*32..w*32+31, two 16-col tiles)
__global__ __launch_bounds__(512) void gemm1_fused(const u16* __restrict__ A,   // [2048][512]
                                                   const u16* __restrict__ BT,  // [256][512]
                                                   const float* __restrict__ al,
                                                   const float* __restrict__ ar,
                                                   u16* __restrict__ GT,        // [256][2048]
                                                   float* __restrict__ el,      // [2048][8]
                                                   float* __restrict__ ert,     // [8][2048]
                                                   unsigned* __restrict__ ermax_u) {
    const int i0 = blockIdx.x * 16;
    const int t = threadIdx.x, lane = t & 63, w = t >> 6;
    const int q = lane >> 4, n = lane & 15;
    const u16* ap = A + (size_t)(i0 + n) * 512 + q * 8;
    const u16* bp0 = BT + (size_t)(w * 32 + n) * 512 + q * 8;
    const u16* bp1 = BT + (size_t)(w * 32 + 16 + n) * 512 + q * 8;
    f32x4 acc0 = {0.f, 0.f, 0.f, 0.f}, acc1 = {0.f, 0.f, 0.f, 0.f};
#pragma unroll
    for (int ks = 0; ks < 16; ++ks) {
        short8 a = *(const short8*)(ap + ks * 32);
        short8 b0 = *(const short8*)(bp0 + ks * 32);
        short8 b1 = *(const short8*)(bp1 + ks * 32);
        acc0 = __builtin_amdgcn_mfma_f32_16x16x32_bf16(a, b0, acc0, 0, 0, 0);
        acc1 = __builtin_amdgcn_mfma_f32_16x16x32_bf16(a, b1, acc1, 0, 0, 0);
    }
    uint2 g0, g1;
    g0.x = bfb(acc0[0]) | (bfb(acc0[1]) << 16);
    g0.y = bfb(acc0[2]) | (bfb(acc0[3]) << 16);
    g1.x = bfb(acc1[0]) | (bfb(acc1[1]) << 16);
    g1.y = bfb(acc1[2]) | (bfb(acc1[3]) << 16);
    *(uint2*)&GT[(size_t)(w * 32 + n) * NN + i0 + q * 4] = g0;
    *(uint2*)&GT[(size_t)(w * 32 + 16 + n) * NN + i0 + q * 4] = g1;
    // el/er: head w, f = n (acc0) and n+16 (acc1); reduce over 16 n-lanes
    const float alv0 = al[n], alv1 = al[n + 16];
    const float arv0 = ar[n], arv1 = ar[n + 16];
    float ermx = -1e30f;
#pragma unroll
    for (int r = 0; r < 4; ++r) {
        float ve = acc0[r] * alv0 + acc1[r] * alv1;
        float vr = acc0[r] * arv0 + acc1[r] * arv1;
#pragma unroll
        for (int off = 8; off; off >>= 1) {
            ve += __shfl_xor(ve, off);
            vr += __shfl_xor(vr, off);
        }
        if (n == 0) {
            el[(size_t)(i0 + q * 4 + r) * 8 + w] = ve;
            ert[(size_t)w * NN + i0 + q * 4 + r] = vr;
            ermx = fmaxf(ermx, vr);
        }
    }
    ermx = fmaxf(ermx, __shfl_xor(ermx, 16));
    ermx = fmaxf(ermx, __shfl_xor(ermx, 32));
    if (lane == 0) atomicMax(&ermax_u[w], fmono(ermx));
}

// ---------------- gemm2 fused: gbt2 = (h@W2)^T bf16, + el2/ert2/ermax2 ----------------
// grid 128 x 512thr: 16 rows x 128 cols; wave w -> col tile w*16
__global__ __launch_bounds__(512) void gemm2_fused(const u16* __restrict__ A,   // [2048][256]
                                                   const u16* __restrict__ BT,  // [128][256]
                                                   const float* __restrict__ al,
                                                   const float* __restrict__ ar,
                                                   u16* __restrict__ GT,        // [128][2048]
                                                   float* __restrict__ el,      // [2048]
                                                   float* __restrict__ ert,     // [2048]
                                                   unsigned* __restrict__ ermax_u) {
    __shared__ float pel[8][16], per_[8][16];
    const int i0 = blockIdx.x * 16;
    const int t = threadIdx.x, lane = t & 63, w = t >> 6;
    const int q = lane >> 4, n = lane & 15;
    const u16* ap = A + (size_t)(i0 + n) * 256 + q * 8;
    const u16* bp = BT + (size_t)(w * 16 + n) * 256 + q * 8;
    f32x4 acc = {0.f, 0.f, 0.f, 0.f};
#pragma unroll
    for (int ks = 0; ks < 8; ++ks) {
        short8 a = *(const short8*)(ap + ks * 32);
        short8 b = *(const short8*)(bp + ks * 32);
        acc = __builtin_amdgcn_mfma_f32_16x16x32_bf16(a, b, acc, 0, 0, 0);
    }
    uint2 g0;
    g0.x = bfb(acc[0]) | (bfb(acc[1]) << 16);
    g0.y = bfb(acc[2]) | (bfb(acc[3]) << 16);
    *(uint2*)&GT[(size_t)(w * 16 + n) * NN + i0 + q * 4] = g0;
    const float alv = al[w * 16 + n], arv = ar[w * 16 + n];
#pragma unroll
    for (int r = 0; r < 4; ++r) {
        float ve = acc[r] * alv;
        float vr = acc[r] * arv;
#pragma unroll
        for (int off = 8; off; off >>= 1) {
            ve += __shfl_xor(ve, off);
            vr += __shfl_xor(vr, off);
        }
        if (n == 0) { pel[w][q * 4 + r] = ve; per_[w][q * 4 + r] = vr; }
    }
    __syncthreads();
    if (t < 16) {
        float se = 0.f, sr = 0.f;
#pragma unroll
        for (int ww = 0; ww < 8; ++ww) { se += pel[ww][t]; sr += per_[ww][t]; }
        el[i0 + t] = se;
        ert[i0 + t] = sr;
        unsigned mm = fmono(sr);
#pragma unroll
        for (int off = 8; off; off >>= 1) {
            unsigned o = (unsigned)__shfl_xor((int)mm, off, 16);
            mm = mm > o ? mm : o;
        }
        if (t == 0) atomicMax(&ermax_u[0], mm);
    }
}

// ---------------- attn1: 16 rows x 4 heads (128 cols), FULL j-range; fused ELU + bf16 out ----------------
// grid (128,2) x 512thr. staging: (m=t>>5, jq=t&31) -> 2 j x 4 heads. MFMA: wave w -> head w>>1, colhalf w&1.
__global__ __launch_bounds__(512) void attn1(const float* __restrict__ el,      // [2048][8]
                                             const float* __restrict__ ert,     // [8][2048]
                                             const unsigned* __restrict__ ermax_u,
                                             const unsigned* __restrict__ ab32, // [2048][64]
                                             const u16* __restrict__ gbt,       // [256][2048]
                                             u16* __restrict__ hbb) {           // [2048][256]
    const int rt = blockIdx.x, sec = blockIdx.y;
    const int i0 = rt * 16, h0 = sec * 4;
    const int t = threadIdx.x, lane = t & 63, w = t >> 6;
    const int q = lane >> 4, n = lane & 15;
    const int m = t >> 5, jq = t & 31;
    const int hl = w >> 1, ch = w & 1;

    __shared__ __align__(16) float ers[4 * 2048];
    __shared__ __align__(16) u16 pl[4][16][72];
    __shared__ unsigned absh[16][64];
    __shared__ float psum_sh[16][4];

#pragma unroll
    for (int c2 = 0; c2 < 4; ++c2)
        *(float4*)&ers[c2 * 2048 + t * 4] = *(const float4*)(ert + (size_t)(h0 + c2) * NN + t * 4);
    for (int c = t; c < 1024; c += 512)
        absh[c >> 6][c & 63] = ab32[(size_t)(i0 + (c >> 6)) * 64 + (c & 63)];

    float elv[4], mxv[4], ps[4];
#pragma unroll
    for (int h = 0; h < 4; ++h) {
        float e = el[(size_t)(i0 + m) * 8 + h0 + h];
        elv[h] = e;
        float mm = e + fmono_inv(ermax_u[h0 + h]);
        mxv[h] = fmaxf(mm, 0.2f * mm);
        ps[h] = 0.f;
    }
    const int col = sec * 128 + hl * 32 + ch * 16 + n;
    const u16* gb = gbt + (size_t)col * NN + q * 8;
    short8 bc0 = *(const short8*)(gb);
    short8 bc1 = *(const short8*)(gb + 32);
    f32x4 acc = {0.f, 0.f, 0.f, 0.f};
    __syncthreads();

    for (int tile = 0; tile < 32; ++tile) {
        const int jt = tile * 64;
        unsigned word = absh[m][tile * 2 + (jq >> 4)];
        unsigned bits = (word >> ((2 * jq) & 31)) & 3u;
#pragma unroll
        for (int h = 0; h < 4; ++h) {
            float2 e2 = *(const float2*)&ers[h * 2048 + jt + 2 * jq];
            float s0 = elv[h] + e2.x, s1 = elv[h] + e2.y;
            s0 = fmaxf(s0, 0.2f * s0) - mxv[h];
            s1 = fmaxf(s1, 0.2f * s1) - mxv[h];
            float p0 = (bits & 1u) ? __expf(s0) : 0.f;
            float p1 = (bits & 2u) ? __expf(s1) : 0.f;
            ps[h] += p0 + p1;
            *(unsigned*)&pl[h][m][2 * jq] = bfb(p0) | (bfb(p1) << 16);
        }
        __syncthreads();
        short8 a0 = *(const short8*)&pl[hl][n][q * 8];
        short8 a1 = *(const short8*)&pl[hl][n][32 + q * 8];
        short8 bn0 = bc0, bn1 = bc1;
        if (tile < 31) {
            bn0 = *(const short8*)(gb + jt + 64);
            bn1 = *(const short8*)(gb + jt + 96);
        }
        acc = __builtin_amdgcn_mfma_f32_16x16x32_bf16(a0, bc0, acc, 0, 0, 0);
        acc = __builtin_amdgcn_mfma_f32_16x16x32_bf16(a1, bc1, acc, 0, 0, 0);
        bc0 = bn0; bc1 = bn1;
        __syncthreads();
    }

#pragma unroll
    for (int h = 0; h < 4; ++h) {
        float v = ps[h];
#pragma unroll
        for (int off = 16; off; off >>= 1) v += __shfl_down(v, off, 32);
        if (jq == 0) psum_sh[m][h] = v;
    }
    __syncthreads();
#pragma unroll
    for (int r = 0; r < 4; ++r) {
        float o = acc[r] / psum_sh[q * 4 + r][hl];
        o = o > 0.f ? o : (__expf(o) - 1.f); // ELU
        hbb[(size_t)(i0 + q * 4 + r) * 256 + col] = (u16)bfb(o);
    }
}

// ---------------- attn2: 16 rows x 64 cols (1 head), FULL j; k-split across wave pairs ----------------
// grid (128,2) x 512thr. wave w: col tile (w>>1)*16, k-half w&1; partials combined via LDS.
__global__ __launch_bounds__(512) void attn2(const float* __restrict__ el,      // [2048]
                                             const float* __restrict__ ert,     // [2048]
                                             const unsigned* __restrict__ ermax_u,
                                             const unsigned* __restrict__ ab32,
                                             const u16* __restrict__ gbt,       // [128][2048]
                                             float* __restrict__ out) {         // [2048][128]
    const int rt = blockIdx.x, sec = blockIdx.y;
    const int i0 = rt * 16;
    const int t = threadIdx.x, lane = t & 63, w = t >> 6;
    const int q = lane >> 4, n = lane & 15;
    const int m = t >> 5, jq = t & 31;
    const int ct = w >> 1, kp = w & 1;

    __shared__ __align__(16) float ers[2048];
    __shared__ __align__(16) u16 pl[16][72];
    __shared__ unsigned absh[16][64];
    __shared__ float psum_sh[16];
    __shared__ float osh[4][16][16];

    *(float4*)&ers[t * 4] = *(const float4*)(ert + t * 4);
    for (int c = t; c < 1024; c += 512)
        absh[c >> 6][c & 63] = ab32[(size_t)(i0 + (c >> 6)) * 64 + (c & 63)];

    const float elv = el[i0 + m];
    float mm = elv + fmono_inv(ermax_u[0]);
    const float mxv = fmaxf(mm, 0.2f * mm);
    const int col = sec * 64 + ct * 16 + n;
    const u16* gb = gbt + (size_t)col * NN + kp * 32 + q * 8;
    short8 bc = *(const short8*)(gb);
    f32x4 acc = {0.f, 0.f, 0.f, 0.f};
    float ps = 0.f;
    __syncthreads();

    for (int tile = 0; tile < 32; ++tile) {
        const int jt = tile * 64;
        unsigned word = absh[m][tile * 2 + (jq >> 4)];
        unsigned bits = (word >> ((2 * jq) & 31)) & 3u;
        float2 e2 = *(const float2*)&ers[jt + 2 * jq];
        float s0 = elv + e2.x, s1 = elv + e2.y;
        s0 = fmaxf(s0, 0.2f * s0) - mxv;
        s1 = fmaxf(s1, 0.2f * s1) - mxv;
        float p0 = (bits & 1u) ? __expf(s0) : 0.f;
        float p1 = (bits & 2u) ? __expf(s1) : 0.f;
        ps += p0 + p1;
        *(unsigned*)&pl[m][2 * jq] = bfb(p0) | (bfb(p1) << 16);
        __syncthreads();
        short8 a = *(const short8*)&pl[n][kp * 32 + q * 8];
        short8 bn = bc;
        if (tile < 31) bn = *(const short8*)(gb + jt + 64);
        acc = __builtin_amdgcn_mfma_f32_16x16x32_bf16(a, bc, acc, 0, 0, 0);
        bc = bn;
        __syncthreads();
    }

#pragma unroll
    for (int off = 16; off; off >>= 1) ps += __shfl_down(ps, off, 32);
    if (jq == 0) psum_sh[m] = ps;
    if (kp == 1) {
#pragma unroll
        for (int r = 0; r < 4; ++r) osh[ct][q * 4 + r][n] = acc[r];
    }
    __syncthreads();
    if (kp == 0) {
#pragma unroll
        for (int r = 0; r < 4; ++r) {
            int mr = q * 4 + r;
            float o = (acc[r] + osh[ct][mr][n]) / psum_sh[mr];
            out[(size_t)(i0 + mr) * 128 + col] = o;
        }
    }
}

extern "C" void kernel_launch(void* const* d_in, const int* in_sizes, int n_in,
                              void* d_out, int out_size, void* d_ws, size_t ws_size,
                              hipStream_t stream) {
    const float* x   = (const float*)d_in[0];
    const float* W1  = (const float*)d_in[1];
    const float* a1l = (const float*)d_in[2];
    const float* a1r = (const float*)d_in[3];
    const float* W2  = (const float*)d_in[4];
    const float* a2l = (const float*)d_in[5];
    const float* a2r = (const float*)d_in[6];
    const int* adj = (const int*)d_in[7];

    char* p = (char*)d_ws;
    u16* xb    = (u16*)p;            p += (size_t)NN * 512 * 2;
    u16* w1t   = (u16*)p;            p += (size_t)256 * 512 * 2;
    u16* w2t   = (u16*)p;            p += (size_t)128 * 256 * 2;
    unsigned* abits = (unsigned*)p;  p += (size_t)NN * 64 * 4;
    u16* gbt1  = (u16*)p;            p += (size_t)256 * NN * 2;
    u16* hbb   = (u16*)p;            p += (size_t)NN * 256 * 2;
    u16* gbt2  = (u16*)p;            p += (size_t)128 * NN * 2;
    float* el1 = (float*)p;          p += (size_t)NN * 8 * 4;
    float* ert1 = (float*)p;         p += (size_t)8 * NN * 4;
    float* el2 = (float*)p;          p += (size_t)NN * 4;
    float* ert2 = (float*)p;         p += (size_t)NN * 4;
    unsigned* ermax1 = (unsigned*)p; // 8 words
    unsigned* ermax2 = ermax1 + 8;   // 1 word

    hipMemsetAsync(ermax1, 0, 16 * sizeof(unsigned), stream);
    prep<<<18048, 256, 0, stream>>>(x, W1, W2, adj, xb, w1t, w2t, (u64*)abits);

    gemm1_fused<<<128, 512, 0, stream>>>(xb, w1t, a1l, a1r, gbt1, el1, ert1, ermax1);
    attn1<<<dim3(128, 2), 512, 0, stream>>>(el1, ert1, ermax1, abits, gbt1, hbb);

    gemm2_fused<<<128, 512, 0, stream>>>(hbb, w2t, a2l, a2r, gbt2, el2, ert2, ermax2);
    attn2<<<dim3(128, 2), 512, 0, stream>>>(el2, ert2, ermax2, abits, gbt2, (float*)d_out);
}

// Round 7
// 133.068 us; speedup vs baseline: 1.2863x; 1.2863x over previous
//
#include <hip/hip_runtime.h>
#include <hip/hip_bf16.h>

#define NN 2048
typedef unsigned short u16;
typedef unsigned long long u64;
typedef __attribute__((ext_vector_type(8))) short short8;
typedef __attribute__((ext_vector_type(4))) float f32x4;

// fp32 -> bf16 bits, RNE
__device__ __forceinline__ unsigned bfb(float x) {
    unsigned u = __float_as_uint(x);
    return (u + 0x7FFFu + ((u >> 16) & 1u)) >> 16;
}

// ---------------- prep: adj bitmask + bf16 conversions (x, W1^T, W2^T), one dispatch ----------------
__global__ __launch_bounds__(256) void prep(const float* __restrict__ x,
                                            const float* __restrict__ W1,
                                            const float* __restrict__ W2,
                                            const int* __restrict__ adj,
                                            u16* __restrict__ xb, u16* __restrict__ w1t,
                                            u16* __restrict__ w2t, u64* __restrict__ ab) {
    const int b = blockIdx.x;
    if (b < 16384) {                         // adj bits
        int t = b * 256 + threadIdx.x;
        int W = t >> 6, lane = t & 63;
        int i = W >> 5, jw = W & 31;
        int a = adj[(size_t)i * NN + jw * 64 + lane];
        u64 m = __ballot(a != 0);
        if (lane == 0) ab[(size_t)i * 32 + jw] = m;
    } else if (b < 16384 + 1024) {           // x: 2048x512 -> bf16
        int t = (b - 16384) * 256 + threadIdx.x;
        float4 v = ((const float4*)x)[t];
        uint2 o;
        o.x = bfb(v.x) | (bfb(v.y) << 16);
        o.y = bfb(v.z) | (bfb(v.w) << 16);
        ((uint2*)xb)[t] = o;
    } else if (b < 16384 + 1024 + 512) {     // w1t[c][k] = W1[k][c]
        int u = (b - 17408) * 256 + threadIdx.x;
        int c = u >> 9, k = u & 511;
        w1t[u] = (u16)bfb(W1[(size_t)k * 256 + c]);
    } else {                                 // w2t[c][k] = W2[k][c]
        int u = (b - 17920) * 256 + threadIdx.x;
        int c = u >> 8, k = u & 255;
        w2t[u] = (u16)bfb(W2[(size_t)k * 128 + c]);
    }
}

// ---------------- gemm1: 16 rows x 32 cols (= head cs), K-split-2; el/ert in epilogue ----------------
// grid (128, 8) x 256 thr. wave w: ct = w&1 (16-col tile), kh = w>>1 (K-half of 512).
__global__ __launch_bounds__(256) void gemm1(const u16* __restrict__ A,   // [2048][512]
                                             const u16* __restrict__ BT,  // [256][512]
                                             const float* __restrict__ al,
                                             const float* __restrict__ ar,
                                             u16* __restrict__ GT,        // [256][2048]
                                             float* __restrict__ el,      // [2048][8]
                                             float* __restrict__ ert) {   // [8][2048]
    const int i0 = blockIdx.x * 16, cs = blockIdx.y;
    const int t = threadIdx.x, lane = t & 63, w = t >> 6;
    const int q = lane >> 4, n = lane & 15;
    const int ct = w & 1, kh = w >> 1;
    __shared__ float osh[2][16][16];
    __shared__ float pel[2][16], per_[2][16];

    const u16* ap = A + (size_t)(i0 + n) * 512 + kh * 256 + q * 8;
    const u16* bp = BT + (size_t)(cs * 32 + ct * 16 + n) * 512 + kh * 256 + q * 8;
    f32x4 acc = {0.f, 0.f, 0.f, 0.f};
#pragma unroll
    for (int ks = 0; ks < 8; ++ks) {
        short8 a = *(const short8*)(ap + ks * 32);
        short8 b = *(const short8*)(bp + ks * 32);
        acc = __builtin_amdgcn_mfma_f32_16x16x32_bf16(a, b, acc, 0, 0, 0);
    }
    if (kh == 1) {
#pragma unroll
        for (int r = 0; r < 4; ++r) osh[ct][q * 4 + r][n] = acc[r];
    }
    __syncthreads();
    if (kh == 0) {
#pragma unroll
        for (int r = 0; r < 4; ++r) acc[r] += osh[ct][q * 4 + r][n];
        uint2 g0;
        g0.x = bfb(acc[0]) | (bfb(acc[1]) << 16);
        g0.y = bfb(acc[2]) | (bfb(acc[3]) << 16);
        *(uint2*)&GT[(size_t)(cs * 32 + ct * 16 + n) * NN + i0 + q * 4] = g0;
        const float alv = al[ct * 16 + n], arv = ar[ct * 16 + n];
#pragma unroll
        for (int r = 0; r < 4; ++r) {
            float ve = acc[r] * alv, vr = acc[r] * arv;
#pragma unroll
            for (int off = 1; off <= 8; off <<= 1) {
                ve += __shfl_xor(ve, off);
                vr += __shfl_xor(vr, off);
            }
            if (n == 0) { pel[ct][q * 4 + r] = ve; per_[ct][q * 4 + r] = vr; }
        }
    }
    __syncthreads();
    if (t < 16) {
        el[(size_t)(i0 + t) * 8 + cs] = pel[0][t] + pel[1][t];
        ert[(size_t)cs * NN + i0 + t] = per_[0][t] + per_[1][t];
    }
}

// ---------------- gemm2: 16 rows x 32 cols of 128, K-split-2; el/ert partials via atomicAdd ----------------
// grid (128, 4) x 256 thr.
__global__ __launch_bounds__(256) void gemm2(const u16* __restrict__ A,   // [2048][256]
                                             const u16* __restrict__ BT,  // [128][256]
                                             const float* __restrict__ al,
                                             const float* __restrict__ ar,
                                             u16* __restrict__ GT,        // [128][2048]
                                             float* __restrict__ el,      // [2048] (zeroed)
                                             float* __restrict__ ert) {   // [2048] (zeroed)
    const int i0 = blockIdx.x * 16, cs = blockIdx.y;
    const int t = threadIdx.x, lane = t & 63, w = t >> 6;
    const int q = lane >> 4, n = lane & 15;
    const int ct = w & 1, kh = w >> 1;
    __shared__ float osh[2][16][16];
    __shared__ float pel[2][16], per_[2][16];

    const u16* ap = A + (size_t)(i0 + n) * 256 + kh * 128 + q * 8;
    const u16* bp = BT + (size_t)(cs * 32 + ct * 16 + n) * 256 + kh * 128 + q * 8;
    f32x4 acc = {0.f, 0.f, 0.f, 0.f};
#pragma unroll
    for (int ks = 0; ks < 4; ++ks) {
        short8 a = *(const short8*)(ap + ks * 32);
        short8 b = *(const short8*)(bp + ks * 32);
        acc = __builtin_amdgcn_mfma_f32_16x16x32_bf16(a, b, acc, 0, 0, 0);
    }
    if (kh == 1) {
#pragma unroll
        for (int r = 0; r < 4; ++r) osh[ct][q * 4 + r][n] = acc[r];
    }
    __syncthreads();
    if (kh == 0) {
#pragma unroll
        for (int r = 0; r < 4; ++r) acc[r] += osh[ct][q * 4 + r][n];
        uint2 g0;
        g0.x = bfb(acc[0]) | (bfb(acc[1]) << 16);
        g0.y = bfb(acc[2]) | (bfb(acc[3]) << 16);
        *(uint2*)&GT[(size_t)(cs * 32 + ct * 16 + n) * NN + i0 + q * 4] = g0;
        const float alv = al[cs * 32 + ct * 16 + n], arv = ar[cs * 32 + ct * 16 + n];
#pragma unroll
        for (int r = 0; r < 4; ++r) {
            float ve = acc[r] * alv, vr = acc[r] * arv;
#pragma unroll
            for (int off = 1; off <= 8; off <<= 1) {
                ve += __shfl_xor(ve, off);
                vr += __shfl_xor(vr, off);
            }
            if (n == 0) { pel[ct][q * 4 + r] = ve; per_[ct][q * 4 + r] = vr; }
        }
    }
    __syncthreads();
    if (t < 16) {
        atomicAdd(&el[i0 + t], pel[0][t] + pel[1][t]);
        atomicAdd(&ert[i0 + t], per_[0][t] + per_[1][t]);
    }
}

// ---------------- attn1: 16 rows x 2 heads (64 cols), full j; local ermax; ELU + bf16 out ----------------
// grid (128, 4) x 512 thr. staging: (m=t>>5, jq=t&31) -> 2 j x 2 heads.
// MFMA roles: hl = w>>2, ch = (w>>1)&1, kf = w&1  (head, col-tile, 32-j k-frag).
__global__ __launch_bounds__(512) void attn1(const float* __restrict__ el,      // [2048][8]
                                             const float* __restrict__ ert,     // [8][2048]
                                             const unsigned* __restrict__ ab32, // [2048][64]
                                             const u16* __restrict__ gbt,       // [256][2048]
                                             u16* __restrict__ hbb) {           // [2048][256]
    const int rt = blockIdx.x, sec = blockIdx.y;
    const int i0 = rt * 16, h0 = sec * 2;
    const int t = threadIdx.x, lane = t & 63, w = t >> 6;
    const int q = lane >> 4, n = lane & 15;
    const int m = t >> 5, jq = t & 31;
    const int hl = w >> 2, ch = (w >> 1) & 1, kf = w & 1;

    __shared__ __align__(16) float ers[2 * 2048];
    __shared__ __align__(16) u16 pl[2][16][72];
    __shared__ unsigned absh[16][64];
    __shared__ float psum_sh[16][2];
    __shared__ float osh[2][2][16][16];
    __shared__ float wmax[2][8];
    __shared__ float mxsh[2];

    float4 v0 = *(const float4*)(ert + (size_t)h0 * NN + t * 4);
    float4 v1 = *(const float4*)(ert + (size_t)(h0 + 1) * NN + t * 4);
    *(float4*)&ers[t * 4] = v0;
    *(float4*)&ers[2048 + t * 4] = v1;
    float m0 = fmaxf(fmaxf(v0.x, v0.y), fmaxf(v0.z, v0.w));
    float m1 = fmaxf(fmaxf(v1.x, v1.y), fmaxf(v1.z, v1.w));
#pragma unroll
    for (int off = 32; off; off >>= 1) {
        m0 = fmaxf(m0, __shfl_xor(m0, off));
        m1 = fmaxf(m1, __shfl_xor(m1, off));
    }
    if (lane == 0) { wmax[0][w] = m0; wmax[1][w] = m1; }
    for (int c = t; c < 1024; c += 512)
        absh[c >> 6][c & 63] = ab32[(size_t)(i0 + (c >> 6)) * 64 + (c & 63)];
    __syncthreads();
    if (t < 2) {
        float mm = wmax[t][0];
#pragma unroll
        for (int ww = 1; ww < 8; ++ww) mm = fmaxf(mm, wmax[t][ww]);
        mxsh[t] = mm;
    }
    __syncthreads();

    float elv[2], mxv[2], ps[2];
#pragma unroll
    for (int h = 0; h < 2; ++h) {
        float e = el[(size_t)(i0 + m) * 8 + h0 + h];
        elv[h] = e;
        float mm = e + mxsh[h];
        mxv[h] = fmaxf(mm, 0.2f * mm);
        ps[h] = 0.f;
    }
    const int col = sec * 64 + hl * 32 + ch * 16 + n;
    const u16* gb = gbt + (size_t)col * NN + kf * 32 + q * 8;
    short8 bc = *(const short8*)gb;
    f32x4 acc = {0.f, 0.f, 0.f, 0.f};

    for (int tile = 0; tile < 32; ++tile) {
        const int jt = tile * 64;
        short8 bn = bc;
        if (tile < 31) bn = *(const short8*)(gb + jt + 64);   // prefetch before staging
        unsigned word = absh[m][tile * 2 + (jq >> 4)];
        unsigned bits = (word >> ((2 * jq) & 31)) & 3u;
#pragma unroll
        for (int h = 0; h < 2; ++h) {
            float2 e2 = *(const float2*)&ers[h * 2048 + jt + 2 * jq];
            float s0 = elv[h] + e2.x, s1 = elv[h] + e2.y;
            s0 = fmaxf(s0, 0.2f * s0) - mxv[h];
            s1 = fmaxf(s1, 0.2f * s1) - mxv[h];
            float p0 = (bits & 1u) ? __expf(s0) : 0.f;
            float p1 = (bits & 2u) ? __expf(s1) : 0.f;
            ps[h] += p0 + p1;
            *(unsigned*)&pl[h][m][2 * jq] = bfb(p0) | (bfb(p1) << 16);
        }
        __syncthreads();
        short8 a = *(const short8*)&pl[hl][n][kf * 32 + q * 8];
        acc = __builtin_amdgcn_mfma_f32_16x16x32_bf16(a, bc, acc, 0, 0, 0);
        bc = bn;
        __syncthreads();
    }

#pragma unroll
    for (int h = 0; h < 2; ++h) {
        float v = ps[h];
#pragma unroll
        for (int off = 16; off; off >>= 1) v += __shfl_down(v, off, 32);
        if (jq == 0) psum_sh[m][h] = v;
    }
    if (kf == 1) {
#pragma unroll
        for (int r = 0; r < 4; ++r) osh[hl][ch][q * 4 + r][n] = acc[r];
    }
    __syncthreads();
    if (kf == 0) {
#pragma unroll
        for (int r = 0; r < 4; ++r) {
            int mr = q * 4 + r;
            float o = (acc[r] + osh[hl][ch][mr][n]) / psum_sh[mr][hl];
            o = o > 0.f ? o : (__expf(o) - 1.f); // ELU
            hbb[(size_t)(i0 + mr) * 256 + col] = (u16)bfb(o);
        }
    }
}

// ---------------- attn2: 16 rows x 32 cols of 128 (1 head), full j; local ermax ----------------
// grid (128, 4) x 512 thr. staging: (m, jq) -> 4 j. MFMA roles: ct = w>>2, kfr = w&3 (32-j k-frag of 128).
__global__ __launch_bounds__(512) void attn2(const float* __restrict__ el,      // [2048]
                                             const float* __restrict__ ert,     // [2048]
                                             const unsigned* __restrict__ ab32,
                                             const u16* __restrict__ gbt,       // [128][2048]
                                             float* __restrict__ out) {         // [2048][128]
    const int rt = blockIdx.x, sec = blockIdx.y;
    const int i0 = rt * 16;
    const int t = threadIdx.x, lane = t & 63, w = t >> 6;
    const int q = lane >> 4, n = lane & 15;
    const int m = t >> 5, jq = t & 31;
    const int ct = w >> 2, kfr = w & 3;

    __shared__ __align__(16) float ers[2048];
    __shared__ __align__(16) u16 pl[16][136];
    __shared__ unsigned absh[16][64];
    __shared__ float psum_sh[16];
    __shared__ float osh[2][3][16][16];
    __shared__ float wmax[8];
    __shared__ float mxsh;

    float4 v0 = *(const float4*)(ert + t * 4);
    *(float4*)&ers[t * 4] = v0;
    float m0 = fmaxf(fmaxf(v0.x, v0.y), fmaxf(v0.z, v0.w));
#pragma unroll
    for (int off = 32; off; off >>= 1) m0 = fmaxf(m0, __shfl_xor(m0, off));
    if (lane == 0) wmax[w] = m0;
    for (int c = t; c < 1024; c += 512)
        absh[c >> 6][c & 63] = ab32[(size_t)(i0 + (c >> 6)) * 64 + (c & 63)];
    __syncthreads();
    if (t == 0) {
        float mm = wmax[0];
#pragma unroll
        for (int ww = 1; ww < 8; ++ww) mm = fmaxf(mm, wmax[ww]);
        mxsh = mm;
    }
    __syncthreads();

    const float elv = el[i0 + m];
    float mm2 = elv + mxsh;
    const float mxv = fmaxf(mm2, 0.2f * mm2);
    float ps = 0.f;
    const int col = sec * 32 + ct * 16 + n;
    const u16* gb = gbt + (size_t)col * NN + kfr * 32 + q * 8;
    short8 bc = *(const short8*)gb;
    f32x4 acc = {0.f, 0.f, 0.f, 0.f};

    for (int tile = 0; tile < 16; ++tile) {
        const int jt = tile * 128;
        short8 bn = bc;
        if (tile < 15) bn = *(const short8*)(gb + jt + 128);
        unsigned word = absh[m][tile * 4 + (jq >> 3)];
        unsigned bits = (word >> ((jq & 7) * 4)) & 0xFu;
        float4 e4 = *(const float4*)&ers[jt + jq * 4];
        float s0 = elv + e4.x, s1 = elv + e4.y, s2 = elv + e4.z, s3 = elv + e4.w;
        s0 = fmaxf(s0, 0.2f * s0) - mxv;
        s1 = fmaxf(s1, 0.2f * s1) - mxv;
        s2 = fmaxf(s2, 0.2f * s2) - mxv;
        s3 = fmaxf(s3, 0.2f * s3) - mxv;
        float p0 = (bits & 1u) ? __expf(s0) : 0.f;
        float p1 = (bits & 2u) ? __expf(s1) : 0.f;
        float p2 = (bits & 4u) ? __expf(s2) : 0.f;
        float p3 = (bits & 8u) ? __expf(s3) : 0.f;
        ps += (p0 + p1) + (p2 + p3);
        uint2 pk;
        pk.x = bfb(p0) | (bfb(p1) << 16);
        pk.y = bfb(p2) | (bfb(p3) << 16);
        *(uint2*)&pl[m][jq * 4] = pk;
        __syncthreads();
        short8 a = *(const short8*)&pl[n][kfr * 32 + q * 8];
        acc = __builtin_amdgcn_mfma_f32_16x16x32_bf16(a, bc, acc, 0, 0, 0);
        bc = bn;
        __syncthreads();
    }

#pragma unroll
    for (int off = 16; off; off >>= 1) ps += __shfl_down(ps, off, 32);
    if (jq == 0) psum_sh[m] = ps;
    if (kfr > 0) {
#pragma unroll
        for (int r = 0; r < 4; ++r) osh[ct][kfr - 1][q * 4 + r][n] = acc[r];
    }
    __syncthreads();
    if (kfr == 0) {
#pragma unroll
        for (int r = 0; r < 4; ++r) {
            int mr = q * 4 + r;
            float o = acc[r] + osh[ct][0][mr][n] + osh[ct][1][mr][n] + osh[ct][2][mr][n];
            out[(size_t)(i0 + mr) * 128 + col] = o / psum_sh[mr];
        }
    }
}

extern "C" void kernel_launch(void* const* d_in, const int* in_sizes, int n_in,
                              void* d_out, int out_size, void* d_ws, size_t ws_size,
                              hipStream_t stream) {
    const float* x   = (const float*)d_in[0];
    const float* W1  = (const float*)d_in[1];
    const float* a1l = (const float*)d_in[2];
    const float* a1r = (const float*)d_in[3];
    const float* W2  = (const float*)d_in[4];
    const float* a2l = (const float*)d_in[5];
    const float* a2r = (const float*)d_in[6];
    const int* adj = (const int*)d_in[7];

    char* p = (char*)d_ws;
    u16* xb    = (u16*)p;            p += (size_t)NN * 512 * 2;
    u16* w1t   = (u16*)p;            p += (size_t)256 * 512 * 2;
    u16* w2t   = (u16*)p;            p += (size_t)128 * 256 * 2;
    unsigned* abits = (unsigned*)p;  p += (size_t)NN * 64 * 4;
    u16* gbt1  = (u16*)p;            p += (size_t)256 * NN * 2;
    u16* hbb   = (u16*)p;            p += (size_t)NN * 256 * 2;
    u16* gbt2  = (u16*)p;            p += (size_t)128 * NN * 2;
    float* el1 = (float*)p;          p += (size_t)NN * 8 * 4;
    float* ert1 = (float*)p;         p += (size_t)8 * NN * 4;
    float* el2 = (float*)p;          p += (size_t)NN * 4;
    float* ert2 = (float*)p;         p += (size_t)NN * 4;

    hipMemsetAsync(el2, 0, 2 * NN * sizeof(float), stream);  // zero el2+ert2 (adjacent)
    prep<<<18048, 256, 0, stream>>>(x, W1, W2, adj, xb, w1t, w2t, (u64*)abits);

    gemm1<<<dim3(128, 8), 256, 0, stream>>>(xb, w1t, a1l, a1r, gbt1, el1, ert1);
    attn1<<<dim3(128, 4), 512, 0, stream>>>(el1, ert1, abits, gbt1, hbb);

    gemm2<<<dim3(128, 4), 256, 0, stream>>>(hbb, w2t, a2l, a2r, gbt2, el2, ert2);
    attn2<<<dim3(128, 4), 512, 0, stream>>>(el2, ert2, abits, gbt2, (float*)d_out);
}

// Round 8
// 130.574 us; speedup vs baseline: 1.3109x; 1.0191x over previous
//
#include <hip/hip_runtime.h>
#include <hip/hip_bf16.h>

#define NN 2048
typedef unsigned short u16;
typedef unsigned long long u64;
typedef __attribute__((ext_vector_type(8))) short short8;
typedef __attribute__((ext_vector_type(4))) float f32x4;

// fp32 -> bf16 bits, RNE
__device__ __forceinline__ unsigned bfb(float x) {
    unsigned u = __float_as_uint(x);
    return (u + 0x7FFFu + ((u >> 16) & 1u)) >> 16;
}
__device__ __forceinline__ unsigned pk2(float a, float b) { return bfb(a) | (bfb(b) << 16); }

// ---------------- prep: adj bitmask + bf16 conversions (x, W1^T, W2^T), one dispatch ----------------
__global__ __launch_bounds__(256) void prep(const float* __restrict__ x,
                                            const float* __restrict__ W1,
                                            const float* __restrict__ W2,
                                            const int* __restrict__ adj,
                                            u16* __restrict__ xb, u16* __restrict__ w1t,
                                            u16* __restrict__ w2t, u64* __restrict__ ab) {
    const int b = blockIdx.x;
    if (b < 16384) {                         // adj bits
        int t = b * 256 + threadIdx.x;
        int W = t >> 6, lane = t & 63;
        int i = W >> 5, jw = W & 31;
        int a = adj[(size_t)i * NN + jw * 64 + lane];
        u64 m = __ballot(a != 0);
        if (lane == 0) ab[(size_t)i * 32 + jw] = m;
    } else if (b < 16384 + 1024) {           // x: 2048x512 -> bf16
        int t = (b - 16384) * 256 + threadIdx.x;
        float4 v = ((const float4*)x)[t];
        uint2 o;
        o.x = pk2(v.x, v.y);
        o.y = pk2(v.z, v.w);
        ((uint2*)xb)[t] = o;
    } else if (b < 16384 + 1024 + 512) {     // w1t[c][k] = W1[k][c]
        int u = (b - 17408) * 256 + threadIdx.x;
        int c = u >> 9, k = u & 511;
        w1t[u] = (u16)bfb(W1[(size_t)k * 256 + c]);
    } else {                                 // w2t[c][k] = W2[k][c]
        int u = (b - 17920) * 256 + threadIdx.x;
        int c = u >> 8, k = u & 255;
        w2t[u] = (u16)bfb(W2[(size_t)k * 128 + c]);
    }
}

// ---------------- gemm1: 16 rows x 32 cols (= head cs), K-split-2; el/ert in epilogue ----------------
__global__ __launch_bounds__(256) void gemm1(const u16* __restrict__ A,   // [2048][512]
                                             const u16* __restrict__ BT,  // [256][512]
                                             const float* __restrict__ al,
                                             const float* __restrict__ ar,
                                             u16* __restrict__ GT,        // [256][2048]
                                             float* __restrict__ el,      // [2048][8]
                                             float* __restrict__ ert) {   // [8][2048]
    const int i0 = blockIdx.x * 16, cs = blockIdx.y;
    const int t = threadIdx.x, lane = t & 63, w = t >> 6;
    const int q = lane >> 4, n = lane & 15;
    const int ct = w & 1, kh = w >> 1;
    __shared__ float osh[2][16][16];
    __shared__ float pel[2][16], per_[2][16];

    const u16* ap = A + (size_t)(i0 + n) * 512 + kh * 256 + q * 8;
    const u16* bp = BT + (size_t)(cs * 32 + ct * 16 + n) * 512 + kh * 256 + q * 8;
    f32x4 acc = {0.f, 0.f, 0.f, 0.f};
#pragma unroll
    for (int ks = 0; ks < 8; ++ks) {
        short8 a = *(const short8*)(ap + ks * 32);
        short8 b = *(const short8*)(bp + ks * 32);
        acc = __builtin_amdgcn_mfma_f32_16x16x32_bf16(a, b, acc, 0, 0, 0);
    }
    if (kh == 1) {
#pragma unroll
        for (int r = 0; r < 4; ++r) osh[ct][q * 4 + r][n] = acc[r];
    }
    __syncthreads();
    if (kh == 0) {
#pragma unroll
        for (int r = 0; r < 4; ++r) acc[r] += osh[ct][q * 4 + r][n];
        uint2 g0;
        g0.x = pk2(acc[0], acc[1]);
        g0.y = pk2(acc[2], acc[3]);
        *(uint2*)&GT[(size_t)(cs * 32 + ct * 16 + n) * NN + i0 + q * 4] = g0;
        const float alv = al[ct * 16 + n], arv = ar[ct * 16 + n];
#pragma unroll
        for (int r = 0; r < 4; ++r) {
            float ve = acc[r] * alv, vr = acc[r] * arv;
#pragma unroll
            for (int off = 1; off <= 8; off <<= 1) {
                ve += __shfl_xor(ve, off);
                vr += __shfl_xor(vr, off);
            }
            if (n == 0) { pel[ct][q * 4 + r] = ve; per_[ct][q * 4 + r] = vr; }
        }
    }
    __syncthreads();
    if (t < 16) {
        el[(size_t)(i0 + t) * 8 + cs] = pel[0][t] + pel[1][t];
        ert[(size_t)cs * NN + i0 + t] = per_[0][t] + per_[1][t];
    }
}

// ---------------- gemm2: 16 rows x 32 cols of 128, K-split-2; el/ert partials via atomicAdd ----------------
__global__ __launch_bounds__(256) void gemm2(const u16* __restrict__ A,   // [2048][256]
                                             const u16* __restrict__ BT,  // [128][256]
                                             const float* __restrict__ al,
                                             const float* __restrict__ ar,
                                             u16* __restrict__ GT,        // [128][2048]
                                             float* __restrict__ el,      // [2048] (zeroed)
                                             float* __restrict__ ert) {   // [2048] (zeroed)
    const int i0 = blockIdx.x * 16, cs = blockIdx.y;
    const int t = threadIdx.x, lane = t & 63, w = t >> 6;
    const int q = lane >> 4, n = lane & 15;
    const int ct = w & 1, kh = w >> 1;
    __shared__ float osh[2][16][16];
    __shared__ float pel[2][16], per_[2][16];

    const u16* ap = A + (size_t)(i0 + n) * 256 + kh * 128 + q * 8;
    const u16* bp = BT + (size_t)(cs * 32 + ct * 16 + n) * 256 + kh * 128 + q * 8;
    f32x4 acc = {0.f, 0.f, 0.f, 0.f};
#pragma unroll
    for (int ks = 0; ks < 4; ++ks) {
        short8 a = *(const short8*)(ap + ks * 32);
        short8 b = *(const short8*)(bp + ks * 32);
        acc = __builtin_amdgcn_mfma_f32_16x16x32_bf16(a, b, acc, 0, 0, 0);
    }
    if (kh == 1) {
#pragma unroll
        for (int r = 0; r < 4; ++r) osh[ct][q * 4 + r][n] = acc[r];
    }
    __syncthreads();
    if (kh == 0) {
#pragma unroll
        for (int r = 0; r < 4; ++r) acc[r] += osh[ct][q * 4 + r][n];
        uint2 g0;
        g0.x = pk2(acc[0], acc[1]);
        g0.y = pk2(acc[2], acc[3]);
        *(uint2*)&GT[(size_t)(cs * 32 + ct * 16 + n) * NN + i0 + q * 4] = g0;
        const float alv = al[cs * 32 + ct * 16 + n], arv = ar[cs * 32 + ct * 16 + n];
#pragma unroll
        for (int r = 0; r < 4; ++r) {
            float ve = acc[r] * alv, vr = acc[r] * arv;
#pragma unroll
            for (int off = 1; off <= 8; off <<= 1) {
                ve += __shfl_xor(ve, off);
                vr += __shfl_xor(vr, off);
            }
            if (n == 0) { pel[ct][q * 4 + r] = ve; per_[ct][q * 4 + r] = vr; }
        }
    }
    __syncthreads();
    if (t < 16) {
        atomicAdd(&el[i0 + t], pel[0][t] + pel[1][t]);
        atomicAdd(&ert[i0 + t], per_[0][t] + per_[1][t]);
    }
}

// ---------------- attn1: 16 rows x 2 heads (64 cols), full j, 128-j tiles, double-buffered pl ----------------
// grid (128,4) x 512 thr. staging: (m=t>>5, jq=t&31) -> 4 j x 2 heads.
// MFMA roles: hl=w>>2 (head), ch=(w>>1)&1 (col-tile), kf2=w&1 (64-j k-frag pair -> 2 MFMAs/tile).
__global__ __launch_bounds__(512) void attn1(const float* __restrict__ el,      // [2048][8]
                                             const float* __restrict__ ert,     // [8][2048]
                                             const unsigned* __restrict__ ab32, // [2048][64]
                                             const u16* __restrict__ gbt,       // [256][2048]
                                             u16* __restrict__ hbb) {           // [2048][256]
    const int rt = blockIdx.x, sec = blockIdx.y;
    const int i0 = rt * 16, h0 = sec * 2;
    const int t = threadIdx.x, lane = t & 63, w = t >> 6;
    const int q = lane >> 4, n = lane & 15;
    const int m = t >> 5, jq = t & 31;
    const int hl = w >> 2, ch = (w >> 1) & 1, kf2 = w & 1;

    __shared__ u16 ersb[2][2048];                     // bf16 er
    __shared__ __align__(16) u16 pl[2][2][16][136];   // [buf][h][m][k]
    __shared__ unsigned absh[16][64];
    __shared__ float psum_sh[16][2];
    __shared__ float osh[2][2][16][16];
    __shared__ float wmax[2][8];
    __shared__ float mxsh[2];

    float4 v0 = *(const float4*)(ert + (size_t)h0 * NN + t * 4);
    float4 v1 = *(const float4*)(ert + (size_t)(h0 + 1) * NN + t * 4);
    uint2 c0, c1;
    c0.x = pk2(v0.x, v0.y); c0.y = pk2(v0.z, v0.w);
    c1.x = pk2(v1.x, v1.y); c1.y = pk2(v1.z, v1.w);
    *(uint2*)&ersb[0][t * 4] = c0;
    *(uint2*)&ersb[1][t * 4] = c1;
    float m0 = fmaxf(fmaxf(v0.x, v0.y), fmaxf(v0.z, v0.w));
    float m1 = fmaxf(fmaxf(v1.x, v1.y), fmaxf(v1.z, v1.w));
#pragma unroll
    for (int off = 32; off; off >>= 1) {
        m0 = fmaxf(m0, __shfl_xor(m0, off));
        m1 = fmaxf(m1, __shfl_xor(m1, off));
    }
    if (lane == 0) { wmax[0][w] = m0; wmax[1][w] = m1; }
    for (int c = t; c < 1024; c += 512)
        absh[c >> 6][c & 63] = ab32[(size_t)(i0 + (c >> 6)) * 64 + (c & 63)];
    __syncthreads();
    if (t < 2) {
        float mm = wmax[t][0];
#pragma unroll
        for (int ww = 1; ww < 8; ++ww) mm = fmaxf(mm, wmax[t][ww]);
        mxsh[t] = mm;
    }
    __syncthreads();

    float elv[2], mxv[2], ps[2];
#pragma unroll
    for (int h = 0; h < 2; ++h) {
        float e = el[(size_t)(i0 + m) * 8 + h0 + h];
        elv[h] = e;
        float mm = e + mxsh[h];
        mxv[h] = fmaxf(mm, 0.2f * mm);
        ps[h] = 0.f;
    }

    auto stage = [&](int tl, int nb) {
        unsigned word = absh[m][tl * 4 + (jq >> 3)];
        unsigned bits = (word >> ((jq & 7) * 4)) & 0xFu;
        const int jo = tl * 128 + jq * 4;
        uint2 raw0 = *(const uint2*)&ersb[0][jo];
        uint2 raw1 = *(const uint2*)&ersb[1][jo];
#pragma unroll
        for (int h = 0; h < 2; ++h) {
            uint2 raw = h ? raw1 : raw0;
            float e0 = __uint_as_float(raw.x << 16);
            float e1 = __uint_as_float(raw.x & 0xFFFF0000u);
            float e2 = __uint_as_float(raw.y << 16);
            float e3 = __uint_as_float(raw.y & 0xFFFF0000u);
            float s0 = elv[h] + e0, s1 = elv[h] + e1, s2 = elv[h] + e2, s3 = elv[h] + e3;
            s0 = fmaxf(s0, 0.2f * s0) - mxv[h];
            s1 = fmaxf(s1, 0.2f * s1) - mxv[h];
            s2 = fmaxf(s2, 0.2f * s2) - mxv[h];
            s3 = fmaxf(s3, 0.2f * s3) - mxv[h];
            float p0 = (bits & 1u) ? __expf(s0) : 0.f;
            float p1 = (bits & 2u) ? __expf(s1) : 0.f;
            float p2 = (bits & 4u) ? __expf(s2) : 0.f;
            float p3 = (bits & 8u) ? __expf(s3) : 0.f;
            ps[h] += (p0 + p1) + (p2 + p3);
            uint2 pkv;
            pkv.x = pk2(p0, p1);
            pkv.y = pk2(p2, p3);
            *(uint2*)&pl[nb][h][m][jq * 4] = pkv;
        }
    };

    const int col = sec * 64 + hl * 32 + ch * 16 + n;
    const u16* gb = gbt + (size_t)col * NN + kf2 * 64 + q * 8;
    short8 bc0 = *(const short8*)gb;
    short8 bc1 = *(const short8*)(gb + 32);
    f32x4 acc = {0.f, 0.f, 0.f, 0.f};

    stage(0, 0);
    __syncthreads();

    for (int tile = 0; tile < 16; ++tile) {
        short8 bn0 = bc0, bn1 = bc1;
        if (tile < 15) {
            bn0 = *(const short8*)(gb + tile * 128 + 128);
            bn1 = *(const short8*)(gb + tile * 128 + 160);
        }
        const u16* ap = &pl[tile & 1][hl][n][kf2 * 64 + q * 8];
        short8 a0 = *(const short8*)ap;
        short8 a1 = *(const short8*)(ap + 32);
        acc = __builtin_amdgcn_mfma_f32_16x16x32_bf16(a0, bc0, acc, 0, 0, 0);
        acc = __builtin_amdgcn_mfma_f32_16x16x32_bf16(a1, bc1, acc, 0, 0, 0);
        if (tile < 15) stage(tile + 1, (tile + 1) & 1);
        bc0 = bn0; bc1 = bn1;
        __syncthreads();
    }

#pragma unroll
    for (int h = 0; h < 2; ++h) {
        float v = ps[h];
#pragma unroll
        for (int off = 16; off; off >>= 1) v += __shfl_down(v, off, 32);
        if (jq == 0) psum_sh[m][h] = v;
    }
    if (kf2 == 1) {
#pragma unroll
        for (int r = 0; r < 4; ++r) osh[hl][ch][q * 4 + r][n] = acc[r];
    }
    __syncthreads();
    if (kf2 == 0) {
#pragma unroll
        for (int r = 0; r < 4; ++r) {
            int mr = q * 4 + r;
            float o = (acc[r] + osh[hl][ch][mr][n]) / psum_sh[mr][hl];
            o = o > 0.f ? o : (__expf(o) - 1.f); // ELU
            hbb[(size_t)(i0 + mr) * 256 + col] = (u16)bfb(o);
        }
    }
}

// ---------------- attn2: 16 rows x 64 cols (1 head), full j, 128-j tiles, double-buffered ----------------
// grid (128,2) x 512 thr. MFMA roles: ct=w>>1 (col-tile), kf2=w&1 (2 MFMAs/tile).
__global__ __launch_bounds__(512) void attn2(const float* __restrict__ el,      // [2048]
                                             const float* __restrict__ ert,     // [2048]
                                             const unsigned* __restrict__ ab32,
                                             const u16* __restrict__ gbt,       // [128][2048]
                                             float* __restrict__ out) {         // [2048][128]
    const int rt = blockIdx.x, sec = blockIdx.y;
    const int i0 = rt * 16;
    const int t = threadIdx.x, lane = t & 63, w = t >> 6;
    const int q = lane >> 4, n = lane & 15;
    const int m = t >> 5, jq = t & 31;
    const int ct = w >> 1, kf2 = w & 1;

    __shared__ u16 ersb[2048];
    __shared__ __align__(16) u16 pl[2][16][136];
    __shared__ unsigned absh[16][64];
    __shared__ float psum_sh[16];
    __shared__ float osh[4][16][16];
    __shared__ float wmax[8];
    __shared__ float mxsh;

    float4 v0 = *(const float4*)(ert + t * 4);
    uint2 c0;
    c0.x = pk2(v0.x, v0.y); c0.y = pk2(v0.z, v0.w);
    *(uint2*)&ersb[t * 4] = c0;
    float m0 = fmaxf(fmaxf(v0.x, v0.y), fmaxf(v0.z, v0.w));
#pragma unroll
    for (int off = 32; off; off >>= 1) m0 = fmaxf(m0, __shfl_xor(m0, off));
    if (lane == 0) wmax[w] = m0;
    for (int c = t; c < 1024; c += 512)
        absh[c >> 6][c & 63] = ab32[(size_t)(i0 + (c >> 6)) * 64 + (c & 63)];
    __syncthreads();
    if (t == 0) {
        float mm = wmax[0];
#pragma unroll
        for (int ww = 1; ww < 8; ++ww) mm = fmaxf(mm, wmax[ww]);
        mxsh = mm;
    }
    __syncthreads();

    const float elv = el[i0 + m];
    float mm2 = elv + mxsh;
    const float mxv = fmaxf(mm2, 0.2f * mm2);
    float ps = 0.f;

    auto stage = [&](int tl, int nb) {
        unsigned word = absh[m][tl * 4 + (jq >> 3)];
        unsigned bits = (word >> ((jq & 7) * 4)) & 0xFu;
        const int jo = tl * 128 + jq * 4;
        uint2 raw = *(const uint2*)&ersb[jo];
        float e0 = __uint_as_float(raw.x << 16);
        float e1 = __uint_as_float(raw.x & 0xFFFF0000u);
        float e2 = __uint_as_float(raw.y << 16);
        float e3 = __uint_as_float(raw.y & 0xFFFF0000u);
        float s0 = elv + e0, s1 = elv + e1, s2 = elv + e2, s3 = elv + e3;
        s0 = fmaxf(s0, 0.2f * s0) - mxv;
        s1 = fmaxf(s1, 0.2f * s1) - mxv;
        s2 = fmaxf(s2, 0.2f * s2) - mxv;
        s3 = fmaxf(s3, 0.2f * s3) - mxv;
        float p0 = (bits & 1u) ? __expf(s0) : 0.f;
        float p1 = (bits & 2u) ? __expf(s1) : 0.f;
        float p2 = (bits & 4u) ? __expf(s2) : 0.f;
        float p3 = (bits & 8u) ? __expf(s3) : 0.f;
        ps += (p0 + p1) + (p2 + p3);
        uint2 pkv;
        pkv.x = pk2(p0, p1);
        pkv.y = pk2(p2, p3);
        *(uint2*)&pl[nb][m][jq * 4] = pkv;
    };

    const int col = sec * 64 + ct * 16 + n;
    const u16* gb = gbt + (size_t)col * NN + kf2 * 64 + q * 8;
    short8 bc0 = *(const short8*)gb;
    short8 bc1 = *(const short8*)(gb + 32);
    f32x4 acc = {0.f, 0.f, 0.f, 0.f};

    stage(0, 0);
    __syncthreads();

    for (int tile = 0; tile < 16; ++tile) {
        short8 bn0 = bc0, bn1 = bc1;
        if (tile < 15) {
            bn0 = *(const short8*)(gb + tile * 128 + 128);
            bn1 = *(const short8*)(gb + tile * 128 + 160);
        }
        const u16* ap = &pl[tile & 1][n][kf2 * 64 + q * 8];
        short8 a0 = *(const short8*)ap;
        short8 a1 = *(const short8*)(ap + 32);
        acc = __builtin_amdgcn_mfma_f32_16x16x32_bf16(a0, bc0, acc, 0, 0, 0);
        acc = __builtin_amdgcn_mfma_f32_16x16x32_bf16(a1, bc1, acc, 0, 0, 0);
        if (tile < 15) stage(tile + 1, (tile + 1) & 1);
        bc0 = bn0; bc1 = bn1;
        __syncthreads();
    }

#pragma unroll
    for (int off = 16; off; off >>= 1) ps += __shfl_down(ps, off, 32);
    if (jq == 0) psum_sh[m] = ps;
    if (kf2 == 1) {
#pragma unroll
        for (int r = 0; r < 4; ++r) osh[ct][q * 4 + r][n] = acc[r];
    }
    __syncthreads();
    if (kf2 == 0) {
#pragma unroll
        for (int r = 0; r < 4; ++r) {
            int mr = q * 4 + r;
            out[(size_t)(i0 + mr) * 128 + col] = (acc[r] + osh[ct][mr][n]) / psum_sh[mr];
        }
    }
}

extern "C" void kernel_launch(void* const* d_in, const int* in_sizes, int n_in,
                              void* d_out, int out_size, void* d_ws, size_t ws_size,
                              hipStream_t stream) {
    const float* x   = (const float*)d_in[0];
    const float* W1  = (const float*)d_in[1];
    const float* a1l = (const float*)d_in[2];
    const float* a1r = (const float*)d_in[3];
    const float* W2  = (const float*)d_in[4];
    const float* a2l = (const float*)d_in[5];
    const float* a2r = (const float*)d_in[6];
    const int* adj = (const int*)d_in[7];

    char* p = (char*)d_ws;
    u16* xb    = (u16*)p;            p += (size_t)NN * 512 * 2;
    u16* w1t   = (u16*)p;            p += (size_t)256 * 512 * 2;
    u16* w2t   = (u16*)p;            p += (size_t)128 * 256 * 2;
    unsigned* abits = (unsigned*)p;  p += (size_t)NN * 64 * 4;
    u16* gbt1  = (u16*)p;            p += (size_t)256 * NN * 2;
    u16* hbb   = (u16*)p;            p += (size_t)NN * 256 * 2;
    u16* gbt2  = (u16*)p;            p += (size_t)128 * NN * 2;
    float* el1 = (float*)p;          p += (size_t)NN * 8 * 4;
    float* ert1 = (float*)p;         p += (size_t)8 * NN * 4;
    float* el2 = (float*)p;          p += (size_t)NN * 4;
    float* ert2 = (float*)p;         p += (size_t)NN * 4;

    hipMemsetAsync(el2, 0, 2 * NN * sizeof(float), stream);  // zero el2+ert2 (adjacent)
    prep<<<18048, 256, 0, stream>>>(x, W1, W2, adj, xb, w1t, w2t, (u64*)abits);

    gemm1<<<dim3(128, 8), 256, 0, stream>>>(xb, w1t, a1l, a1r, gbt1, el1, ert1);
    attn1<<<dim3(128, 4), 512, 0, stream>>>(el1, ert1, abits, gbt1, hbb);

    gemm2<<<dim3(128, 4), 256, 0, stream>>>(hbb, w2t, a2l, a2r, gbt2, el2, ert2);
    attn2<<<dim3(128, 2), 512, 0, stream>>>(el2, ert2, abits, gbt2, (float*)d_out);
}